// Round 3
// baseline (50.446 us; speedup 1.0000x reference)
//
#include <hip/hip_runtime.h>
#include <math.h>

#define NH    16384   // Hadamard size (2^14)
#define NRES  8192
#define NINP  64
#define BATCH 512

// Physical LDS float-index: phys = idx ^ (g<<2), g = idx[5:7]^idx[8:10]^idx[11:13].
// Bijective; leaves bits 0-1 intact (float4 order preserved). For all 12
// layouts below the lane->quadbank map (phys bits 2-4) is rank-3 => every
// b128 access is conflict-free (8 lanes per quad-bank, the minimum).
__device__ __forceinline__ constexpr int gfold(int v) {
    return ((v >> 5) & 7) ^ ((v >> 8) & 7) ^ ((v >> 11) & 7);
}
__device__ __forceinline__ constexpr int physf(int v) {
    return v ^ (gfold(v) << 2);
}

template <int S>
__device__ __forceinline__ void stage32(float x[32]) {
#pragma unroll
    for (int i = 0; i < 32; ++i) {
        if (!(i & S)) {
            float a = x[i], b = x[i | S];
            x[i]     = a + b;
            x[i | S] = a - b;
        }
    }
}

// Exchange helpers. Q = physf(runtime base), OFF = compile-time j-offset
// (fields disjoint => physf(base|off) = physf(base) ^ physf(off)).
#define WRX(Q, OFF) do { _Pragma("unroll") \
    for (int j = 0; j < 8; ++j) \
        lds4[(unsigned)((Q) ^ physf(OFF)) >> 2] = \
            make_float4(x[4*j+0], x[4*j+1], x[4*j+2], x[4*j+3]); } while (0)

#define RDX(Q, OFF) do { _Pragma("unroll") \
    for (int j = 0; j < 8; ++j) { \
        float4 v = lds4[(unsigned)((Q) ^ physf(OFF)) >> 2]; \
        x[4*j+0] = v.x; x[4*j+1] = v.y; x[4*j+2] = v.z; x[4*j+3] = v.w; } } while (0)

// In-wave LDS write->read ordering (wave-private region, no s_barrier needed).
#define WAVE_SYNC() asm volatile("s_waitcnt lgkmcnt(0)" ::: "memory")

// Layouts (idx bits): v=bits{0,1} in-float4. Runs share wave-bit positions:
//  R1 (P1-P3):  w@{11-13}   R2 (P4-P6): w@{8-10}
//  R3 (P7-P9):  w@{5-7}     R4 (P10-P12): w@{10-12}
// P1:  l@{5-10}            E{2,3,4}   (load layout: idx = t*32+f)
// P2:  l@{2-4,8-10}        E{5,6,7}
// P3:  l@{2-7}             E{8,9,10}
// P4:  l@{2-7}             E{11,12,13}  (diag1 here)
// P5:  l@{5-7,11-13}       E{2,3,4}
// P6:  l@{2-4,11-13}       E{5,6,7}
// P7:  l@{2-4,11-13}       E{8,9,10}
// P8:  l@{2-4,8-10}        E{11,12,13}  (diag2 here)
// P9:  l@{2-4,8-9,13}      E{10,11,12}
// P10: l@{2-3,7-9,13}      E{4,5,6}
// P11: l@{2-6,13}          E{7,8,9}
// P12: l@{4-9}             E{2,3,13}    (epilogue: contiguous 4KB/wave store)

__global__ __launch_bounds__(512, 4) void st_kernel(
    const float* __restrict__ state, const float* __restrict__ inputs,
    const float* __restrict__ bias,  const float* __restrict__ diag,
    float* __restrict__ out)
{
    __shared__ float4 lds4[NH / 4];
    const int t = threadIdx.x;   // 0..511
    const int r = blockIdx.x;    // 0..511
    const int l = t & 63, w = t >> 6;

    // Layout bases (runtime, per-thread) -> pre-swizzled Q values.
    const int Q1  = physf((l << 5) | (w << 11));
    const int Q2  = physf(((l & 7) << 2) | ((l >> 3) << 8) | (w << 11));
    const int Q3  = physf((l << 2) | (w << 11));
    const int b4  = (l << 2) | (w << 8);
    const int Q4  = physf(b4);
    const int Q5  = physf(((l & 7) << 5) | ((l >> 3) << 11) | (w << 8));
    const int Q6  = physf(((l & 7) << 2) | ((l >> 3) << 11) | (w << 8));
    const int Q7  = physf(((l & 7) << 2) | ((l >> 3) << 11) | (w << 5));
    const int b8  = ((l & 7) << 2) | ((l >> 3) << 8) | (w << 5);
    const int Q8  = physf(b8);
    const int Q9  = physf(((l & 7) << 2) | (((l >> 3) & 3) << 8) | ((l >> 5) << 13) | (w << 5));
    const int Q10 = physf(((l & 3) << 2) | (((l >> 2) & 7) << 7) | ((l >> 5) << 13) | (w << 10));
    const int Q11 = physf(((l & 31) << 2) | ((l >> 5) << 13) | (w << 10));
    const int Q12 = physf((l << 4) | (w << 10));
    const int b12 = (l << 4) | (w << 10);   // epilogue global index base

    float x[32];

    // ---------- initial load, P1 layout: idx = t*32 + f ----------
    if (t < 256) {
        const float* srow = state + (size_t)r * NRES + t * 32;
#pragma unroll
        for (int g = 0; g < 8; ++g) {
            float4 v = *(const float4*)(srow + g * 4);
            x[g*4+0] = 0.9f * v.x; x[g*4+1] = 0.9f * v.y;
            x[g*4+2] = 0.9f * v.z; x[g*4+3] = 0.9f * v.w;
        }
    } else if (t < 258) {
        const float* irow = inputs + r * NINP + (t - 256) * 32;
#pragma unroll
        for (int g = 0; g < 8; ++g) {
            float4 v = *(const float4*)(irow + g * 4);
            x[g*4+0] = 0.4f * v.x; x[g*4+1] = 0.4f * v.y;
            x[g*4+2] = 0.4f * v.z; x[g*4+3] = 0.4f * v.w;
        }
    } else {
#pragma unroll
        for (int e = 0; e < 32; ++e) x[e] = 0.f;
    }
    if (t < 258) {   // diag layer 0 (values beyond 8256 are zero anyway)
        const float* d0 = diag + t * 32;
#pragma unroll
        for (int g = 0; g < 8; ++g) {
            float4 dv = *(const float4*)(d0 + g * 4);
            x[g*4+0] *= dv.x; x[g*4+1] *= dv.y;
            x[g*4+2] *= dv.z; x[g*4+3] *= dv.w;
        }
    }

    // prefetch diag1 (consumed at P4, ~3 passes later)
    float4 d1v[8];
    {
        const float* d1 = diag + NH + b4;
#pragma unroll
        for (int j = 0; j < 8; ++j) d1v[j] = *(const float4*)(d1 + (j << 11));
    }

    // ---------- P1: layer0 bits 0-4 ----------
    stage32<1>(x); stage32<2>(x); stage32<4>(x); stage32<8>(x); stage32<16>(x);

    WRX(Q1, (j << 2));          // E1 (intra)
    WAVE_SYNC();
    RDX(Q2, (j << 5));
    stage32<4>(x); stage32<8>(x); stage32<16>(x);   // P2: layer0 bits 5-7

    WRX(Q2, (j << 5));          // E2 (intra)
    WAVE_SYNC();
    RDX(Q3, (j << 8));
    stage32<4>(x); stage32<8>(x); stage32<16>(x);   // P3: layer0 bits 8-10

    WRX(Q3, (j << 8));          // E3 (INTER: w 11-13 -> 8-10)
    __syncthreads();
    RDX(Q4, (j << 11));
    stage32<4>(x); stage32<8>(x); stage32<16>(x);   // P4: layer0 bits 11-13
    {   // diag layer 1 (idx = b4 | j<<11 | v)
#pragma unroll
        for (int j = 0; j < 8; ++j) {
            x[4*j+0] *= d1v[j].x; x[4*j+1] *= d1v[j].y;
            x[4*j+2] *= d1v[j].z; x[4*j+3] *= d1v[j].w;
        }
    }
    stage32<1>(x); stage32<2>(x);                   // layer1 bits 0-1

    // prefetch diag2 (consumed at P8)
    float4 d2v[8];
    {
        const float* d2 = diag + 2 * NH + b8;
#pragma unroll
        for (int j = 0; j < 8; ++j) d2v[j] = *(const float4*)(d2 + (j << 11));
    }

    WRX(Q4, (j << 11));         // E4 (intra)
    WAVE_SYNC();
    RDX(Q5, (j << 2));
    stage32<4>(x); stage32<8>(x); stage32<16>(x);   // P5: layer1 bits 2-4

    WRX(Q5, (j << 2));          // E5 (intra)
    WAVE_SYNC();
    RDX(Q6, (j << 5));
    stage32<4>(x); stage32<8>(x); stage32<16>(x);   // P6: layer1 bits 5-7

    WRX(Q6, (j << 5));          // E6 (INTER: w 8-10 -> 5-7)
    __syncthreads();
    RDX(Q7, (j << 8));
    stage32<4>(x); stage32<8>(x); stage32<16>(x);   // P7: layer1 bits 8-10

    WRX(Q7, (j << 8));          // E7 (intra)
    WAVE_SYNC();
    RDX(Q8, (j << 11));
    stage32<4>(x); stage32<8>(x); stage32<16>(x);   // P8: layer1 bits 11-13
    {   // diag layer 2 (idx = b8 | j<<11 | v)
#pragma unroll
        for (int j = 0; j < 8; ++j) {
            x[4*j+0] *= d2v[j].x; x[4*j+1] *= d2v[j].y;
            x[4*j+2] *= d2v[j].z; x[4*j+3] *= d2v[j].w;
        }
    }
    stage32<1>(x); stage32<2>(x);                   // layer2 bits 0-1

    // prefetch bias (consumed in epilogue; idx = b12 | j01<<2 | v)
    float4 bv[4];
#pragma unroll
    for (int j = 0; j < 4; ++j) bv[j] = *(const float4*)(bias + b12 + (j << 2));

    WRX(Q8, (j << 11));         // E8 (intra)
    WAVE_SYNC();
    RDX(Q9, (j << 10));
    stage32<4>(x); stage32<8>(x); stage32<16>(x);   // P9: layer2 bits 10-12

    WRX(Q9, (j << 10));         // E9 (INTER: w 5-7 -> 10-12)
    __syncthreads();
    RDX(Q10, (j << 4));
    stage32<4>(x); stage32<8>(x); stage32<16>(x);   // P10: layer2 bits 4-6

    WRX(Q10, (j << 4));         // E10 (intra)
    WAVE_SYNC();
    RDX(Q11, (j << 7));
    stage32<4>(x); stage32<8>(x); stage32<16>(x);   // P11: layer2 bits 7-9

    WRX(Q11, (j << 7));         // E11 (intra)
    WAVE_SYNC();
    RDX(Q12, (((j & 3) << 2) | ((j >> 2) << 13)));
    stage32<4>(x); stage32<8>(x); stage32<16>(x);   // P12: layer2 bits 2,3,13

    // ---------- epilogue: idx bit13 = x-flat bit4 = 0 -> x[0..15] ----------
    // m = w*1024 + l*16 + j*4 + v  (per-wave contiguous 4 KB store)
    {
        float* orow = out + (size_t)r * NRES;
        const float inv = 1.0f / (float)NH;
#pragma unroll
        for (int j = 0; j < 4; ++j) {
            float4 o;
            o.x = erff(x[4*j+0] * inv + bv[j].x);
            o.y = erff(x[4*j+1] * inv + bv[j].y);
            o.z = erff(x[4*j+2] * inv + bv[j].z);
            o.w = erff(x[4*j+3] * inv + bv[j].w);
            *(float4*)(orow + b12 + (j << 2)) = o;
        }
    }
}

extern "C" void kernel_launch(void* const* d_in, const int* in_sizes, int n_in,
                              void* d_out, int out_size, void* d_ws, size_t ws_size,
                              hipStream_t stream) {
    (void)in_sizes; (void)n_in; (void)out_size; (void)d_ws; (void)ws_size;
    const float* state  = (const float*)d_in[0];
    const float* inputs = (const float*)d_in[1];
    const float* bias   = (const float*)d_in[2];
    const float* diag   = (const float*)d_in[3];
    float* out = (float*)d_out;

    hipLaunchKernelGGL(st_kernel, dim3(BATCH), dim3(512), 0, stream,
                       state, inputs, bias, diag, out);
}

// Round 4
// 33.393 us; speedup vs baseline: 1.5107x; 1.5107x over previous
//
#include <hip/hip_runtime.h>
#include <math.h>

#define NH    16384   // Hadamard size (2^14)
#define NRES  8192
#define NINP  64
#define BATCH 512

// Physical LDS float-index: phys = idx ^ (g<<2), g = idx[5:7]^idx[8:10]^idx[11:13].
// Bijective; leaves bits 0-1 intact (float4 order preserved). For all 12
// layouts below the lane->quadbank map (phys bits 2-4) is rank-3 in lane bits
// => every b128 access is ~conflict-free (8 lanes per quad-bank).
__device__ __forceinline__ constexpr int gfold(int v) {
    return ((v >> 5) & 7) ^ ((v >> 8) & 7) ^ ((v >> 11) & 7);
}
__device__ __forceinline__ constexpr int physf(int v) {
    return v ^ (gfold(v) << 2);
}

template <int S>
__device__ __forceinline__ void stage32(float x[32]) {
#pragma unroll
    for (int i = 0; i < 32; ++i) {
        if (!(i & S)) {
            float a = x[i], b = x[i | S];
            x[i]     = a + b;
            x[i | S] = a - b;
        }
    }
}

// Exchange helpers. Q = physf(runtime base), OFF = compile-time j-offset
// (fields disjoint => physf(base|off) = physf(base) ^ physf(off)).
#define WRX(Q, OFF) do { _Pragma("unroll") \
    for (int j = 0; j < 8; ++j) \
        lds4[(unsigned)((Q) ^ physf(OFF)) >> 2] = \
            make_float4(x[4*j+0], x[4*j+1], x[4*j+2], x[4*j+3]); } while (0)

#define RDX(Q, OFF) do { _Pragma("unroll") \
    for (int j = 0; j < 8; ++j) { \
        float4 v = lds4[(unsigned)((Q) ^ physf(OFF)) >> 2]; \
        x[4*j+0] = v.x; x[4*j+1] = v.y; x[4*j+2] = v.z; x[4*j+3] = v.w; } } while (0)

// In-wave LDS write->read ordering (wave-private region, no s_barrier needed).
#define WAVE_SYNC() asm volatile("s_waitcnt lgkmcnt(0)" ::: "memory")

// Layouts (idx bits): v=bits{0,1} in-float4. Runs share wave-bit positions:
//  R1 (P1-P3):  w@{11-13}   R2 (P4-P6): w@{8-10}
//  R3 (P7-P9):  w@{5-7}     R4 (P10-P12): w@{10-12}
// P1:  l@{5-10}   j@{2-4}    P2:  l@{2-4,8-10} j@{5-7}   P3: l@{2-7}  j@{8-10}
// P4:  l@{2-7}    j@{11-13}  (diag1)
// P5:  l@{5-7,11-13} j@{2-4} P6:  l@{2-4,11-13} j@{5-7}  P7: l@{2-4,11-13} j@{8-10}
// P8:  l@{2-4,8-10}  j@{11-13} (diag2)
// P9:  l@{2-4,8-9,13} j@{10-12}
// P10: l@{2-3,7-9,13} j@{4-6} P11: l@{2-6,13} j@{7-9}
// P12: l@{4-9} j@{2,3,13}    (epilogue: contiguous 4KB/wave store)

__global__ __launch_bounds__(512, 2) void st_kernel(
    const float* __restrict__ state, const float* __restrict__ inputs,
    const float* __restrict__ bias,  const float* __restrict__ diag,
    float* __restrict__ out)
{
    __shared__ float4 lds4[NH / 4];
    const int t = threadIdx.x;   // 0..511
    const int r = blockIdx.x;    // 0..511
    const int l = t & 63, w = t >> 6;

    float x[32];

    // ---------- initial load, P1 layout: idx = t*32 + f ----------
    if (t < 256) {
        const float* srow = state + (size_t)r * NRES + t * 32;
#pragma unroll
        for (int g = 0; g < 8; ++g) {
            float4 v = *(const float4*)(srow + g * 4);
            x[g*4+0] = 0.9f * v.x; x[g*4+1] = 0.9f * v.y;
            x[g*4+2] = 0.9f * v.z; x[g*4+3] = 0.9f * v.w;
        }
    } else if (t < 258) {
        const float* irow = inputs + r * NINP + (t - 256) * 32;
#pragma unroll
        for (int g = 0; g < 8; ++g) {
            float4 v = *(const float4*)(irow + g * 4);
            x[g*4+0] = 0.4f * v.x; x[g*4+1] = 0.4f * v.y;
            x[g*4+2] = 0.4f * v.z; x[g*4+3] = 0.4f * v.w;
        }
    } else {
#pragma unroll
        for (int e = 0; e < 32; ++e) x[e] = 0.f;
    }
    if (t < 258) {   // diag layer 0 (values beyond 8256 are zero anyway)
        const float* d0 = diag + t * 32;
#pragma unroll
        for (int g = 0; g < 8; ++g) {
            float4 dv = *(const float4*)(d0 + g * 4);
            x[g*4+0] *= dv.x; x[g*4+1] *= dv.y;
            x[g*4+2] *= dv.z; x[g*4+3] *= dv.w;
        }
    }

    // ---------- P1: layer0 bits 0-4 ----------
    stage32<1>(x); stage32<2>(x); stage32<4>(x); stage32<8>(x); stage32<16>(x);

    // E1 (intra-run): P1 -> P2
    { const int Qw = physf((l << 5) | (w << 11)); WRX(Qw, (j << 2)); }
    WAVE_SYNC();
    { const int Qr = physf(((l & 7) << 2) | ((l >> 3) << 8) | (w << 11)); RDX(Qr, (j << 5)); }
    stage32<4>(x); stage32<8>(x); stage32<16>(x);   // P2: layer0 bits 5-7

    // E2 (intra): P2 -> P3
    { const int Qw = physf(((l & 7) << 2) | ((l >> 3) << 8) | (w << 11)); WRX(Qw, (j << 5)); }
    WAVE_SYNC();
    { const int Qr = physf((l << 2) | (w << 11)); RDX(Qr, (j << 8)); }

    // prefetch diag1 (consumed at P4, one exchange away)
    float4 pf[8];
    {
        const float* d1 = diag + NH + ((l << 2) | (w << 8));
#pragma unroll
        for (int j = 0; j < 8; ++j) pf[j] = *(const float4*)(d1 + (j << 11));
    }

    stage32<4>(x); stage32<8>(x); stage32<16>(x);   // P3: layer0 bits 8-10

    // E3 (INTER: w 11-13 -> 8-10): P3 -> P4
    { const int Qw = physf((l << 2) | (w << 11)); WRX(Qw, (j << 8)); }
    __syncthreads();
    { const int Qr = physf((l << 2) | (w << 8)); RDX(Qr, (j << 11)); }
    stage32<4>(x); stage32<8>(x); stage32<16>(x);   // P4: layer0 bits 11-13
#pragma unroll
    for (int j = 0; j < 8; ++j) {                   // diag layer 1
        x[4*j+0] *= pf[j].x; x[4*j+1] *= pf[j].y;
        x[4*j+2] *= pf[j].z; x[4*j+3] *= pf[j].w;
    }
    stage32<1>(x); stage32<2>(x);                   // layer1 bits 0-1

    // E4 (intra): P4 -> P5
    { const int Qw = physf((l << 2) | (w << 8)); WRX(Qw, (j << 11)); }
    WAVE_SYNC();
    { const int Qr = physf(((l & 7) << 5) | ((l >> 3) << 11) | (w << 8)); RDX(Qr, (j << 2)); }
    stage32<4>(x); stage32<8>(x); stage32<16>(x);   // P5: layer1 bits 2-4

    // E5 (intra): P5 -> P6
    { const int Qw = physf(((l & 7) << 5) | ((l >> 3) << 11) | (w << 8)); WRX(Qw, (j << 2)); }
    WAVE_SYNC();
    { const int Qr = physf(((l & 7) << 2) | ((l >> 3) << 11) | (w << 8)); RDX(Qr, (j << 5)); }
    stage32<4>(x); stage32<8>(x); stage32<16>(x);   // P6: layer1 bits 5-7

    // E6 (INTER: w 8-10 -> 5-7): P6 -> P7
    { const int Qw = physf(((l & 7) << 2) | ((l >> 3) << 11) | (w << 8)); WRX(Qw, (j << 5)); }
    __syncthreads();
    { const int Qr = physf(((l & 7) << 2) | ((l >> 3) << 11) | (w << 5)); RDX(Qr, (j << 8)); }

    // prefetch diag2 (consumed at P8, one exchange away)
    {
        const float* d2 = diag + 2 * NH + (((l & 7) << 2) | ((l >> 3) << 8) | (w << 5));
#pragma unroll
        for (int j = 0; j < 8; ++j) pf[j] = *(const float4*)(d2 + (j << 11));
    }

    stage32<4>(x); stage32<8>(x); stage32<16>(x);   // P7: layer1 bits 8-10

    // E7 (intra): P7 -> P8
    { const int Qw = physf(((l & 7) << 2) | ((l >> 3) << 11) | (w << 5)); WRX(Qw, (j << 8)); }
    WAVE_SYNC();
    { const int Qr = physf(((l & 7) << 2) | ((l >> 3) << 8) | (w << 5)); RDX(Qr, (j << 11)); }
    stage32<4>(x); stage32<8>(x); stage32<16>(x);   // P8: layer1 bits 11-13
#pragma unroll
    for (int j = 0; j < 8; ++j) {                   // diag layer 2
        x[4*j+0] *= pf[j].x; x[4*j+1] *= pf[j].y;
        x[4*j+2] *= pf[j].z; x[4*j+3] *= pf[j].w;
    }
    stage32<1>(x); stage32<2>(x);                   // layer2 bits 0-1

    // E8 (intra): P8 -> P9
    { const int Qw = physf(((l & 7) << 2) | ((l >> 3) << 8) | (w << 5)); WRX(Qw, (j << 11)); }
    WAVE_SYNC();
    { const int Qr = physf(((l & 7) << 2) | (((l >> 3) & 3) << 8) | ((l >> 5) << 13) | (w << 5));
      RDX(Qr, (j << 10)); }
    stage32<4>(x); stage32<8>(x); stage32<16>(x);   // P9: layer2 bits 10-12

    // E9 (INTER: w 5-7 -> 10-12): P9 -> P10
    { const int Qw = physf(((l & 7) << 2) | (((l >> 3) & 3) << 8) | ((l >> 5) << 13) | (w << 5));
      WRX(Qw, (j << 10)); }
    __syncthreads();
    { const int Qr = physf(((l & 3) << 2) | (((l >> 2) & 7) << 7) | ((l >> 5) << 13) | (w << 10));
      RDX(Qr, (j << 4)); }
    stage32<4>(x); stage32<8>(x); stage32<16>(x);   // P10: layer2 bits 4-6

    // E10 (intra): P10 -> P11
    { const int Qw = physf(((l & 3) << 2) | (((l >> 2) & 7) << 7) | ((l >> 5) << 13) | (w << 10));
      WRX(Qw, (j << 4)); }
    WAVE_SYNC();
    { const int Qr = physf(((l & 31) << 2) | ((l >> 5) << 13) | (w << 10)); RDX(Qr, (j << 7)); }

    // prefetch bias (consumed in epilogue; idx = b12 | j01<<2 | v), one exchange away
    float4 bv[4];
    {
        const int b12 = (l << 4) | (w << 10);
#pragma unroll
        for (int j = 0; j < 4; ++j) bv[j] = *(const float4*)(bias + b12 + (j << 2));
    }

    stage32<4>(x); stage32<8>(x); stage32<16>(x);   // P11: layer2 bits 7-9

    // E11 (intra): P11 -> P12
    { const int Qw = physf(((l & 31) << 2) | ((l >> 5) << 13) | (w << 10)); WRX(Qw, (j << 7)); }
    WAVE_SYNC();
    { const int Qr = physf((l << 4) | (w << 10)); RDX(Qr, (((j & 3) << 2) | ((j >> 2) << 13))); }
    stage32<4>(x); stage32<8>(x); stage32<16>(x);   // P12: layer2 bits 2,3,13

    // ---------- epilogue: idx bit13 = x-flat bit4 = 0 -> x[0..15] ----------
    // idx = w*1024 + l*16 + j*4 + v  (per-wave contiguous 4 KB store)
    {
        float* orow = out + (size_t)r * NRES;
        const int b12 = (l << 4) | (w << 10);
        const float inv = 1.0f / (float)NH;
#pragma unroll
        for (int j = 0; j < 4; ++j) {
            float4 o;
            o.x = erff(x[4*j+0] * inv + bv[j].x);
            o.y = erff(x[4*j+1] * inv + bv[j].y);
            o.z = erff(x[4*j+2] * inv + bv[j].z);
            o.w = erff(x[4*j+3] * inv + bv[j].w);
            *(float4*)(orow + b12 + (j << 2)) = o;
        }
    }
}

extern "C" void kernel_launch(void* const* d_in, const int* in_sizes, int n_in,
                              void* d_out, int out_size, void* d_ws, size_t ws_size,
                              hipStream_t stream) {
    (void)in_sizes; (void)n_in; (void)out_size; (void)d_ws; (void)ws_size;
    const float* state  = (const float*)d_in[0];
    const float* inputs = (const float*)d_in[1];
    const float* bias   = (const float*)d_in[2];
    const float* diag   = (const float*)d_in[3];
    float* out = (float*)d_out;

    hipLaunchKernelGGL(st_kernel, dim3(BATCH), dim3(512), 0, stream,
                       state, inputs, bias, diag, out);
}

// Round 5
// 29.070 us; speedup vs baseline: 1.7353x; 1.1487x over previous
//
#include <hip/hip_runtime.h>
#include <math.h>

#define NH    16384   // Hadamard size (2^14)
#define NRES  8192
#define NINP  64
#define BATCH 512

// Physical LDS float-index: phys = idx ^ (g<<2), g = idx[5:7]^idx[8:10]^idx[11:13].
// Bijective; leaves bits 0-1 intact (float4 order preserved). All 4 thread-
// layouts below give a rank-3 lane->quadbank (phys[2:4]) map => b128 conflict-free:
//  T_A: c=(l2^l5, l0^l3, l1^l4)  T_B: c=(l0^l3^l5, l1, l2^l4)
//  T_C: c=(l0^l3, l1^l4, l2^l5)  T_D: c=(l3, l0^l4, l1^l2^l5)
__device__ __forceinline__ constexpr int gfold(int v) {
    return ((v >> 5) & 7) ^ ((v >> 8) & 7) ^ ((v >> 11) & 7);
}
__device__ __forceinline__ constexpr int physf(int v) {
    return v ^ (gfold(v) << 2);
}

template <int S>
__device__ __forceinline__ void stage64(float x[64]) {
#pragma unroll
    for (int i = 0; i < 64; ++i) {
        if (!(i & S)) {
            float a = x[i], b = x[i | S];
            x[i]     = a + b;
            x[i | S] = a - b;
        }
    }
}

// Exchange helpers: Q = physf(runtime thread base), OFF = compile-time j-field
// offset (disjoint bit-fields => physf(base|off) = physf(base)^physf(off)).
#define WRX(Q, OFF) do { _Pragma("unroll") \
    for (int j = 0; j < 16; ++j) \
        lds4[(unsigned)((Q) ^ physf(OFF)) >> 2] = \
            make_float4(x[4*j+0], x[4*j+1], x[4*j+2], x[4*j+3]); } while (0)

#define RDX(Q, OFF) do { _Pragma("unroll") \
    for (int j = 0; j < 16; ++j) { \
        float4 v = lds4[(unsigned)((Q) ^ physf(OFF)) >> 2]; \
        x[4*j+0] = v.x; x[4*j+1] = v.y; x[4*j+2] = v.z; x[4*j+3] = v.w; } } while (0)

// In-wave LDS write->read ordering (wave-private region, no s_barrier needed).
#define WAVE_SYNC() asm volatile("s_waitcnt lgkmcnt(0)" ::: "memory")

// 256 threads (t = w<<6 | l, w: 2 wave bits, l: 6 lane bits), 64 floats/thread
// (f = j<<2 | v; v = idx bits 0-1 always).  Thread layouts (idx bit homes):
//  T_A: j@{2-5},  l@{6-11}, w@{12,13}   base = t<<6
//  T_B: j@{6-9},  l@{2-5}+{10,11}, w@{12,13}   base = (l&15)<<2 | (l>>4)<<10 | w<<12
//  T_C: j@{10-13}, l@{2-7}, w@{8,9}    base = l<<2 | w<<8
//  T_D: j@{2-5},  l@{6,7}+{10-13}, w@{8,9}   base = (l&3)<<6 | (l>>2)<<10 | w<<8
// Pass plan (42 stages total):
//  P1=T_A: layer0 bits 0-5   | E1 intra -> P2=T_B: layer0 6-9
//  E2 INTER -> P3=T_C: layer0 10-13, diag1, layer1 {0,1,10-13}
//  E3 intra -> P4=T_D: layer1 2-5
//  E4 INTER -> P5=T_B: layer1 6-9, diag2, layer2 {0,1,6-9}
//  E5 intra -> P6=T_A: layer2 2-5
//  E6 INTER -> P7=T_C: layer2 10-13, epilogue (f bit5 = idx13 = 0 -> x[0..31])

__global__ __launch_bounds__(256, 2) void st_kernel(
    const float* __restrict__ state, const float* __restrict__ inputs,
    const float* __restrict__ bias,  const float* __restrict__ diag,
    float* __restrict__ out)
{
    __shared__ float4 lds4[NH / 4];
    const int t = threadIdx.x;   // 0..255
    const int r = blockIdx.x;    // 0..511
    const int l = t & 63, w = t >> 6;

    const int bB = ((l & 15) << 2) | ((l >> 4) << 10) | (w << 12);
    const int bC = (l << 2) | (w << 8);

    float x[64];

    // ---------- initial load, T_A layout: idx = t*64 + f ----------
    if (t < 128) {
        const float* srow = state + (size_t)r * NRES + t * 64;
        const float* d0   = diag + t * 64;
#pragma unroll
        for (int j = 0; j < 16; ++j) {
            float4 v = *(const float4*)(srow + 4 * j);
            float4 d = *(const float4*)(d0 + 4 * j);
            x[4*j+0] = 0.9f * v.x * d.x; x[4*j+1] = 0.9f * v.y * d.y;
            x[4*j+2] = 0.9f * v.z * d.z; x[4*j+3] = 0.9f * v.w * d.w;
        }
    } else if (t == 128) {
        const float* irow = inputs + r * NINP;     // idx 8192..8255
        const float* d0   = diag + 8192;
#pragma unroll
        for (int j = 0; j < 16; ++j) {
            float4 v = *(const float4*)(irow + 4 * j);
            float4 d = *(const float4*)(d0 + 4 * j);
            x[4*j+0] = 0.4f * v.x * d.x; x[4*j+1] = 0.4f * v.y * d.y;
            x[4*j+2] = 0.4f * v.z * d.z; x[4*j+3] = 0.4f * v.w * d.w;
        }
    } else {
#pragma unroll
        for (int e = 0; e < 64; ++e) x[e] = 0.f;
    }

    // ---------- P1: layer0 bits 0-5 ----------
    stage64<1>(x); stage64<2>(x); stage64<4>(x);
    stage64<8>(x); stage64<16>(x); stage64<32>(x);

    // E1 (intra): T_A -> T_B
    { const int Q = physf(t << 6); WRX(Q, (j << 2)); }
    WAVE_SYNC();
    { const int Q = physf(bB); RDX(Q, (j << 6)); }
    stage64<4>(x); stage64<8>(x); stage64<16>(x); stage64<32>(x);  // layer0 6-9

    // E2 (INTER): T_B -> T_C
    { const int Q = physf(bB); WRX(Q, (j << 6)); }
    __syncthreads();
    { const int Q = physf(bC); RDX(Q, (j << 10)); }

    // prefetch diag layer1 (T_C layout: idx = bC | j<<10 | v)
    float4 pf[16];
    {
        const float* d1 = diag + NH + bC;
#pragma unroll
        for (int j = 0; j < 16; ++j) pf[j] = *(const float4*)(d1 + (j << 10));
    }
    stage64<4>(x); stage64<8>(x); stage64<16>(x); stage64<32>(x);  // layer0 10-13
#pragma unroll
    for (int j = 0; j < 16; ++j) {                                  // diag1
        x[4*j+0] *= pf[j].x; x[4*j+1] *= pf[j].y;
        x[4*j+2] *= pf[j].z; x[4*j+3] *= pf[j].w;
    }
    stage64<1>(x); stage64<2>(x);                                   // layer1 0-1
    stage64<4>(x); stage64<8>(x); stage64<16>(x); stage64<32>(x);  // layer1 10-13

    // E3 (intra): T_C -> T_D
    { const int Q = physf(bC); WRX(Q, (j << 10)); }
    WAVE_SYNC();
    { const int Q = physf(((l & 3) << 6) | ((l >> 2) << 10) | (w << 8)); RDX(Q, (j << 2)); }
    stage64<4>(x); stage64<8>(x); stage64<16>(x); stage64<32>(x);  // layer1 2-5

    // E4 (INTER): T_D -> T_B
    { const int Q = physf(((l & 3) << 6) | ((l >> 2) << 10) | (w << 8)); WRX(Q, (j << 2)); }
    __syncthreads();
    { const int Q = physf(bB); RDX(Q, (j << 6)); }

    // prefetch diag layer2 (T_B layout: idx = bB | j<<6 | v)
    {
        const float* d2 = diag + 2 * NH + bB;
#pragma unroll
        for (int j = 0; j < 16; ++j) pf[j] = *(const float4*)(d2 + (j << 6));
    }
    stage64<4>(x); stage64<8>(x); stage64<16>(x); stage64<32>(x);  // layer1 6-9
#pragma unroll
    for (int j = 0; j < 16; ++j) {                                  // diag2
        x[4*j+0] *= pf[j].x; x[4*j+1] *= pf[j].y;
        x[4*j+2] *= pf[j].z; x[4*j+3] *= pf[j].w;
    }
    stage64<1>(x); stage64<2>(x);                                   // layer2 0-1
    stage64<4>(x); stage64<8>(x); stage64<16>(x); stage64<32>(x);  // layer2 6-9

    // E5 (intra): T_B -> T_A
    { const int Q = physf(bB); WRX(Q, (j << 6)); }
    WAVE_SYNC();
    { const int Q = physf(t << 6); RDX(Q, (j << 2)); }
    stage64<4>(x); stage64<8>(x); stage64<16>(x); stage64<32>(x);  // layer2 2-5

    // E6 (INTER): T_A -> T_C
    { const int Q = physf(t << 6); WRX(Q, (j << 2)); }
    __syncthreads();
    { const int Q = physf(bC); RDX(Q, (j << 10)); }

    // prefetch bias (T_C layout, output half j<8: m = bC | j<<10 | v)
    float4 bv[8];
#pragma unroll
    for (int j = 0; j < 8; ++j) bv[j] = *(const float4*)(bias + bC + (j << 10));

    stage64<4>(x); stage64<8>(x); stage64<16>(x); stage64<32>(x);  // layer2 10-13

    // ---------- epilogue: f bit5 = idx13 = 0 -> x[0..31] ----------
    {
        float* orow = out + (size_t)r * NRES;
        const float inv = 1.0f / (float)NH;
#pragma unroll
        for (int j = 0; j < 8; ++j) {
            float4 o;
            o.x = erff(x[4*j+0] * inv + bv[j].x);
            o.y = erff(x[4*j+1] * inv + bv[j].y);
            o.z = erff(x[4*j+2] * inv + bv[j].z);
            o.w = erff(x[4*j+3] * inv + bv[j].w);
            *(float4*)(orow + bC + (j << 10)) = o;
        }
    }
}

extern "C" void kernel_launch(void* const* d_in, const int* in_sizes, int n_in,
                              void* d_out, int out_size, void* d_ws, size_t ws_size,
                              hipStream_t stream) {
    (void)in_sizes; (void)n_in; (void)out_size; (void)d_ws; (void)ws_size;
    const float* state  = (const float*)d_in[0];
    const float* inputs = (const float*)d_in[1];
    const float* bias   = (const float*)d_in[2];
    const float* diag   = (const float*)d_in[3];
    float* out = (float*)d_out;

    hipLaunchKernelGGL(st_kernel, dim3(BATCH), dim3(256), 0, stream,
                       state, inputs, bias, diag, out);
}